// Round 1
// baseline (208.111 us; speedup 1.0000x reference)
//
#include <hip/hip_runtime.h>

typedef _Float16 f16x8 __attribute__((ext_vector_type(8)));
typedef float f32x4 __attribute__((ext_vector_type(4)));

#define GF(r) ((((r)&3)) ^ (((r)>>2)&3))

#define GLD16(gp, lp) __builtin_amdgcn_global_load_lds( \
    (const __attribute__((address_space(1))) void*)(gp), \
    (__attribute__((address_space(3))) void*)(lp), 16, 0, 0)

// ---------------- kernel 1: x -> fp16, and fp32 passthrough copy ----------------
__global__ void cvt_x_kernel(const float4* __restrict__ x4, f16x8* __restrict__ xh,
                             float4* __restrict__ xc, int n8) {
    int i = blockIdx.x * 256 + threadIdx.x;
    if (i >= n8) return;
    float4 a = x4[2 * i], b = x4[2 * i + 1];
    xc[2 * i] = a;
    xc[2 * i + 1] = b;
    f16x8 h;
    h[0] = (_Float16)a.x; h[1] = (_Float16)a.y; h[2] = (_Float16)a.z; h[3] = (_Float16)a.w;
    h[4] = (_Float16)b.x; h[5] = (_Float16)b.y; h[6] = (_Float16)b.z; h[7] = (_Float16)b.w;
    xh[i] = h;
}

// ---------------- kernel 2: W -> W^T fp16 (wt[mat][n][k]) ----------------
__global__ void cvt_w_kernel(const float* __restrict__ Wq, const float* __restrict__ Wk,
                             const float* __restrict__ Wv, _Float16* __restrict__ wt) {
    int j = blockIdx.x * 256 + threadIdx.x;   // 3*512*512 = 786432
    if (j >= 786432) return;
    int mat = j >> 18;
    int r = (j >> 9) & 511;   // k index (input row)
    int n = j & 511;          // output column
    const float* W = (mat == 0) ? Wq : ((mat == 1) ? Wk : Wv);
    float v = W[r * 512 + n];
    wt[(size_t)mat * 262144 + (size_t)n * 512 + r] = (_Float16)v;
}

// ---------------- kernel 3: QKV projection GEMM (fp16 MFMA) ----------------
// x[8192x512] * W[512x512] -> q/k row-major fp16 [8192][512]; v transposed:
// vt[(h*4+b)*64 + d][2048] per (h,b).
__global__ __launch_bounds__(256, 2) void gemm_qkv(
    const _Float16* __restrict__ xh, const _Float16* __restrict__ wt,
    _Float16* __restrict__ qh, _Float16* __restrict__ kh, _Float16* __restrict__ vt) {
    __shared__ _Float16 lA[128 * 32];
    __shared__ _Float16 lB[128 * 32];
    const int mat = blockIdx.y;
    const _Float16* wp = wt + (size_t)mat * 262144;
    const int mtile = blockIdx.x >> 2, ntile = blockIdx.x & 3;
    const int tid = threadIdx.x, lane = tid & 63;
    const int g = lane >> 4, c = lane & 15;
    const int wid = tid >> 6, wm = wid >> 1, wn = wid & 1;

    f32x4 acc[4][4];
#pragma unroll
    for (int i = 0; i < 4; ++i)
#pragma unroll
        for (int j = 0; j < 4; ++j) acc[i][j] = (f32x4){0.f, 0.f, 0.f, 0.f};

    const int row0 = tid >> 2, p0 = tid & 3;

    for (int ks = 0; ks < 16; ++ks) {
        __syncthreads();
        {
            int r = row0, pp = p0 ^ GF(r);
            GLD16(xh + (size_t)(mtile * 128 + r) * 512 + ks * 32 + pp * 8, &lA[tid * 8]);
            GLD16(wp + (size_t)(ntile * 128 + r) * 512 + ks * 32 + pp * 8, &lB[tid * 8]);
            r = 64 + row0; pp = p0 ^ GF(r);
            GLD16(xh + (size_t)(mtile * 128 + r) * 512 + ks * 32 + pp * 8, &lA[(256 + tid) * 8]);
            GLD16(wp + (size_t)(ntile * 128 + r) * 512 + ks * 32 + pp * 8, &lB[(256 + tid) * 8]);
        }
        __syncthreads();
        f16x8 af[4], bf[4];
#pragma unroll
        for (int i = 0; i < 4; ++i) {
            int ra = wm * 64 + i * 16 + c;
            af[i] = *(const f16x8*)&lA[ra * 32 + ((g ^ GF(ra)) * 8)];
            int rb = wn * 64 + i * 16 + c;
            bf[i] = *(const f16x8*)&lB[rb * 32 + ((g ^ GF(rb)) * 8)];
        }
#pragma unroll
        for (int mi = 0; mi < 4; ++mi)
#pragma unroll
            for (int ni = 0; ni < 4; ++ni)
                acc[mi][ni] = __builtin_amdgcn_mfma_f32_16x16x32_f16(af[mi], bf[ni], acc[mi][ni], 0, 0, 0);
    }

#pragma unroll
    for (int mi = 0; mi < 4; ++mi)
#pragma unroll
        for (int ni = 0; ni < 4; ++ni)
#pragma unroll
            for (int r = 0; r < 4; ++r) {
                int m = mtile * 128 + wm * 64 + mi * 16 + g * 4 + r;
                int n = ntile * 128 + wn * 64 + ni * 16 + c;
                _Float16 hv = (_Float16)acc[mi][ni][r];
                if (mat == 0) {
                    qh[(size_t)m * 512 + n] = hv;
                } else if (mat == 1) {
                    kh[(size_t)m * 512 + n] = hv;
                } else {
                    // v transposed: vt[((h*4 + b)*64 + d)*2048 + s]
                    int h = n >> 6, d = n & 63, bb = m >> 11, s = m & 2047;
                    vt[(((size_t)h * 4 + bb) * 64 + d) * 2048 + s] = hv;
                }
            }
}

// ---------------- kernel 4: flash attention ----------------
// grid 512: xcd-grouped (h,b); 4 waves x 32 q-rows = 128 q-rows per block.
__global__ __launch_bounds__(256, 2) void attn_kernel(
    const _Float16* __restrict__ qh, const _Float16* __restrict__ kh,
    const _Float16* __restrict__ vt, float* __restrict__ out) {
    __shared__ _Float16 pb[4][32 * 64];

    const int bid = blockIdx.x;
    const int xcd = bid & 7, idx = bid >> 3;
    const int hb = xcd + 8 * (idx >> 4);  // 0..31
    const int qb = idx & 15;
    const int h = hb >> 2, b = hb & 3;
    const int tid = threadIdx.x, lane = tid & 63, wid = tid >> 6;
    const int g = lane >> 4, c = lane & 15;

    const _Float16* qp = qh + ((size_t)b * 2048 + qb * 128 + wid * 32) * 512 + h * 64;
    const _Float16* kp = kh + (size_t)b * 2048 * 512 + h * 64;
    const _Float16* vp = vt + (size_t)hb * 64 * 2048;
    _Float16* myp = pb[wid];

    // Q fragments, hoisted (A-frag: row = c (+16*ms), k = g*8 (+32*kc))
    f16x8 aQ[2][2];
#pragma unroll
    for (int ms = 0; ms < 2; ++ms)
#pragma unroll
        for (int kc = 0; kc < 2; ++kc)
            aQ[ms][kc] = *(const f16x8*)(qp + (size_t)(ms * 16 + c) * 512 + kc * 32 + g * 8);

    float mrow[2][4], lrow[2][4];
    f32x4 o[2][4];
#pragma unroll
    for (int ms = 0; ms < 2; ++ms)
#pragma unroll
        for (int r = 0; r < 4; ++r) {
            mrow[ms][r] = -1e30f;
            lrow[ms][r] = 0.f;
        }
#pragma unroll
    for (int ms = 0; ms < 2; ++ms)
#pragma unroll
        for (int d = 0; d < 4; ++d) o[ms][d] = (f32x4){0.f, 0.f, 0.f, 0.f};

    for (int kt = 0; kt < 32; ++kt) {
        const _Float16* ktp = kp + (size_t)kt * 64 * 512;
        // ---- QK^T ----
        f32x4 s[2][4];
#pragma unroll
        for (int ks = 0; ks < 4; ++ks) {
            f16x8 bk0 = *(const f16x8*)(ktp + (size_t)(ks * 16 + c) * 512 + g * 8);
            f16x8 bk1 = *(const f16x8*)(ktp + (size_t)(ks * 16 + c) * 512 + 32 + g * 8);
#pragma unroll
            for (int ms = 0; ms < 2; ++ms) {
                f32x4 z = (f32x4){0.f, 0.f, 0.f, 0.f};
                z = __builtin_amdgcn_mfma_f32_16x16x32_f16(aQ[ms][0], bk0, z, 0, 0, 0);
                z = __builtin_amdgcn_mfma_f32_16x16x32_f16(aQ[ms][1], bk1, z, 0, 0, 0);
                s[ms][ks] = z;
            }
        }
        // ---- online softmax (wave-parallel; rows live in 16-lane groups) ----
        float sc[2][4];
#pragma unroll
        for (int ms = 0; ms < 2; ++ms)
#pragma unroll
            for (int r = 0; r < 4; ++r) {
                float pm = fmaxf(fmaxf(s[ms][0][r], s[ms][1][r]),
                                 fmaxf(s[ms][2][r], s[ms][3][r]));
                pm = fmaxf(pm, __shfl_xor(pm, 1));
                pm = fmaxf(pm, __shfl_xor(pm, 2));
                pm = fmaxf(pm, __shfl_xor(pm, 4));
                pm = fmaxf(pm, __shfl_xor(pm, 8));
                float nm = fmaxf(mrow[ms][r], pm);
                float e = __expf(mrow[ms][r] - nm);
                mrow[ms][r] = nm;
                sc[ms][r] = e;
                float rs = 0.f;
#pragma unroll
                for (int ks = 0; ks < 4; ++ks) {
                    float p = __expf(s[ms][ks][r] - nm);
                    s[ms][ks][r] = p;
                    rs += p;
                }
                rs += __shfl_xor(rs, 1);
                rs += __shfl_xor(rs, 2);
                rs += __shfl_xor(rs, 4);
                rs += __shfl_xor(rs, 8);
                lrow[ms][r] = lrow[ms][r] * e + rs;
            }
        // ---- P -> LDS (fp16, swizzled) ----
#pragma unroll
        for (int ms = 0; ms < 2; ++ms)
#pragma unroll
            for (int ks = 0; ks < 4; ++ks)
#pragma unroll
                for (int r = 0; r < 4; ++r) {
                    int row = ms * 16 + g * 4 + r;
                    int col = ks * 16 + c;
                    int ch = (col >> 3) ^ (row & 7);
                    myp[row * 64 + ch * 8 + (col & 7)] = (_Float16)s[ms][ks][r];
                }
        asm volatile("s_waitcnt lgkmcnt(0)" ::: "memory");
        // ---- P A-frags ----
        f16x8 aP[2][2];
#pragma unroll
        for (int ms = 0; ms < 2; ++ms)
#pragma unroll
            for (int kc = 0; kc < 2; ++kc) {
                int row = ms * 16 + c;
                int ch = (kc * 4 + g) ^ (row & 7);
                aP[ms][kc] = *(const f16x8*)&myp[row * 64 + ch * 8];
            }
        // ---- rescale O, then PV ----
#pragma unroll
        for (int ms = 0; ms < 2; ++ms)
#pragma unroll
            for (int d = 0; d < 4; ++d)
#pragma unroll
                for (int r = 0; r < 4; ++r) o[ms][d][r] *= sc[ms][r];
        const _Float16* vtp = vp + kt * 64;
#pragma unroll
        for (int d = 0; d < 4; ++d) {
            f16x8 bv0 = *(const f16x8*)(vtp + (size_t)(d * 16 + c) * 2048 + g * 8);
            f16x8 bv1 = *(const f16x8*)(vtp + (size_t)(d * 16 + c) * 2048 + 32 + g * 8);
#pragma unroll
            for (int ms = 0; ms < 2; ++ms) {
                o[ms][d] = __builtin_amdgcn_mfma_f32_16x16x32_f16(aP[ms][0], bv0, o[ms][d], 0, 0, 0);
                o[ms][d] = __builtin_amdgcn_mfma_f32_16x16x32_f16(aP[ms][1], bv1, o[ms][d], 0, 0, 0);
            }
        }
        asm volatile("s_waitcnt lgkmcnt(0)" ::: "memory");
    }
    // ---- epilogue: divide by l, store fp32 ----
#pragma unroll
    for (int ms = 0; ms < 2; ++ms)
#pragma unroll
        for (int d = 0; d < 4; ++d)
#pragma unroll
            for (int r = 0; r < 4; ++r) {
                int qrow = qb * 128 + wid * 32 + ms * 16 + g * 4 + r;
                out[((size_t)b * 2048 + qrow) * 512 + h * 64 + d * 16 + c] =
                    o[ms][d][r] / lrow[ms][r];
            }
}

extern "C" void kernel_launch(void* const* d_in, const int* in_sizes, int n_in,
                              void* d_out, int out_size, void* d_ws, size_t ws_size,
                              hipStream_t stream) {
    const float* x = (const float*)d_in[0];
    const float* Wq = (const float*)d_in[1];
    const float* Wk = (const float*)d_in[2];
    const float* Wv = (const float*)d_in[3];
    float* out = (float*)d_out;
    float* xcopy = out + 4194304;

    char* ws = (char*)d_ws;
    _Float16* xh = (_Float16*)ws;                       // 8 MB
    _Float16* wt = (_Float16*)(ws + (size_t)(10u << 20));  // 1.5 MB (after 8MB xh + pad)
    _Float16* qh = (_Float16*)(ws + (size_t)(12u << 20));  // 8 MB
    _Float16* kh = (_Float16*)(ws + (size_t)(20u << 20));  // 8 MB
    _Float16* vt = (_Float16*)(ws + (size_t)(28u << 20));  // 8 MB

    cvt_x_kernel<<<2048, 256, 0, stream>>>((const float4*)x, (f16x8*)xh, (float4*)xcopy, 524288);
    cvt_w_kernel<<<3072, 256, 0, stream>>>(Wq, Wk, Wv, wt);
    gemm_qkv<<<dim3(256, 3), 256, 0, stream>>>(xh, wt, qh, kh, vt);
    attn_kernel<<<512, 256, 0, stream>>>(qh, kh, vt, out);
}

// Round 2
// 145.886 us; speedup vs baseline: 1.4265x; 1.4265x over previous
//
#include <hip/hip_runtime.h>

typedef _Float16 f16x8 __attribute__((ext_vector_type(8)));
typedef float f32x4 __attribute__((ext_vector_type(4)));

#define GF(r) ((((r)&3)) ^ (((r)>>2)&3))

#define GLD16(gp, lp) __builtin_amdgcn_global_load_lds( \
    (const __attribute__((address_space(1))) void*)(gp), \
    (__attribute__((address_space(3))) void*)(lp), 16, 0, 0)

// ---------------- kernel 1: x -> fp16, and fp32 passthrough copy ----------------
__global__ void cvt_x_kernel(const float4* __restrict__ x4, f16x8* __restrict__ xh,
                             float4* __restrict__ xc, int n8) {
    int i = blockIdx.x * 256 + threadIdx.x;
    if (i >= n8) return;
    float4 a = x4[2 * i], b = x4[2 * i + 1];
    xc[2 * i] = a;
    xc[2 * i + 1] = b;
    f16x8 h;
    h[0] = (_Float16)a.x; h[1] = (_Float16)a.y; h[2] = (_Float16)a.z; h[3] = (_Float16)a.w;
    h[4] = (_Float16)b.x; h[5] = (_Float16)b.y; h[6] = (_Float16)b.z; h[7] = (_Float16)b.w;
    xh[i] = h;
}

// ---------------- kernel 2: W -> W^T fp16 (wt[mat][n][k]) ----------------
__global__ void cvt_w_kernel(const float* __restrict__ Wq, const float* __restrict__ Wk,
                             const float* __restrict__ Wv, _Float16* __restrict__ wt) {
    int j = blockIdx.x * 256 + threadIdx.x;   // 3*512*512 = 786432
    if (j >= 786432) return;
    int mat = j >> 18;
    int r = (j >> 9) & 511;   // k index (input row)
    int n = j & 511;          // output column
    const float* W = (mat == 0) ? Wq : ((mat == 1) ? Wk : Wv);
    float v = W[r * 512 + n];
    wt[(size_t)mat * 262144 + (size_t)n * 512 + r] = (_Float16)v;
}

// ---------------- kernel 3: QKV projection GEMM (fp16 MFMA) ----------------
__global__ __launch_bounds__(256, 2) void gemm_qkv(
    const _Float16* __restrict__ xh, const _Float16* __restrict__ wt,
    _Float16* __restrict__ qh, _Float16* __restrict__ kh, _Float16* __restrict__ vt) {
    __shared__ _Float16 lA[128 * 32];
    __shared__ _Float16 lB[128 * 32];
    const int mat = blockIdx.y;
    const _Float16* wp = wt + (size_t)mat * 262144;
    const int mtile = blockIdx.x >> 2, ntile = blockIdx.x & 3;
    const int tid = threadIdx.x, lane = tid & 63;
    const int g = lane >> 4, c = lane & 15;
    const int wid = tid >> 6, wm = wid >> 1, wn = wid & 1;

    f32x4 acc[4][4];
#pragma unroll
    for (int i = 0; i < 4; ++i)
#pragma unroll
        for (int j = 0; j < 4; ++j) acc[i][j] = (f32x4){0.f, 0.f, 0.f, 0.f};

    const int row0 = tid >> 2, p0 = tid & 3;

    for (int ks = 0; ks < 16; ++ks) {
        __syncthreads();
        {
            int r = row0, pp = p0 ^ GF(r);
            GLD16(xh + (size_t)(mtile * 128 + r) * 512 + ks * 32 + pp * 8, &lA[tid * 8]);
            GLD16(wp + (size_t)(ntile * 128 + r) * 512 + ks * 32 + pp * 8, &lB[tid * 8]);
            r = 64 + row0; pp = p0 ^ GF(r);
            GLD16(xh + (size_t)(mtile * 128 + r) * 512 + ks * 32 + pp * 8, &lA[(256 + tid) * 8]);
            GLD16(wp + (size_t)(ntile * 128 + r) * 512 + ks * 32 + pp * 8, &lB[(256 + tid) * 8]);
        }
        __syncthreads();
        f16x8 af[4], bf[4];
#pragma unroll
        for (int i = 0; i < 4; ++i) {
            int ra = wm * 64 + i * 16 + c;
            af[i] = *(const f16x8*)&lA[ra * 32 + ((g ^ GF(ra)) * 8)];
            int rb = wn * 64 + i * 16 + c;
            bf[i] = *(const f16x8*)&lB[rb * 32 + ((g ^ GF(rb)) * 8)];
        }
#pragma unroll
        for (int mi = 0; mi < 4; ++mi)
#pragma unroll
            for (int ni = 0; ni < 4; ++ni)
                acc[mi][ni] = __builtin_amdgcn_mfma_f32_16x16x32_f16(af[mi], bf[ni], acc[mi][ni], 0, 0, 0);
    }

#pragma unroll
    for (int mi = 0; mi < 4; ++mi)
#pragma unroll
        for (int ni = 0; ni < 4; ++ni)
#pragma unroll
            for (int r = 0; r < 4; ++r) {
                int m = mtile * 128 + wm * 64 + mi * 16 + g * 4 + r;
                int n = ntile * 128 + wn * 64 + ni * 16 + c;
                _Float16 hv = (_Float16)acc[mi][ni][r];
                if (mat == 0) {
                    qh[(size_t)m * 512 + n] = hv;
                } else if (mat == 1) {
                    kh[(size_t)m * 512 + n] = hv;
                } else {
                    int h = n >> 6, d = n & 63, bb = m >> 11, s = m & 2047;
                    vt[(((size_t)h * 4 + bb) * 64 + d) * 2048 + s] = hv;
                }
            }
}

// ---------------- kernel 4: flash attention ----------------
// grid 1024: xcd-grouped (h,b); 4 waves x 16 q-rows = 64 q-rows per block.
// K/V tiles (64 keys) staged in LDS, double-buffered, swizzled.
__global__ __launch_bounds__(256, 4) void attn_kernel(
    const _Float16* __restrict__ qh, const _Float16* __restrict__ kh,
    const _Float16* __restrict__ vt, float* __restrict__ out) {
    __shared__ _Float16 lK[2][64 * 64];   // [key][dh], chunk-swizzled
    __shared__ _Float16 lV[2][64 * 64];   // [dh][key], chunk-swizzled
    __shared__ _Float16 lP[4][16 * 64];   // per-wave P buffer

    const int bid = blockIdx.x;
    const int xcd = bid & 7, idx = bid >> 3;     // idx 0..127
    const int hb = xcd * 4 + (idx >> 5);         // 0..31 (4 hb per XCD)
    const int qb = idx & 31;                     // 0..31
    const int h = hb >> 2, b = hb & 3;
    const int tid = threadIdx.x, lane = tid & 63, wid = tid >> 6;
    const int g = lane >> 4, c = lane & 15;

    const _Float16* qp = qh + ((size_t)b * 2048 + qb * 64 + wid * 16) * 512 + h * 64;
    const _Float16* kp = kh + (size_t)b * 2048 * 512 + h * 64;
    const _Float16* vp = vt + (size_t)hb * 64 * 2048;
    _Float16* myp = lP[wid];

    // staging geometry: chunk ci = tid (+256); row = ci>>3, p = ci&7, src chunk p^(row&7)
    const int srow = tid >> 3;                 // 0..31 (second chunk: +32)
    const int ssw = (tid & 7) ^ (srow & 7);    // same for row and row+32

#define STAGE(buf, kt) do { \
    GLD16(kp + ((size_t)((kt) * 64 + srow) * 512) + ssw * 8, &lK[buf][tid * 8]); \
    GLD16(kp + ((size_t)((kt) * 64 + srow + 32) * 512) + ssw * 8, &lK[buf][(tid + 256) * 8]); \
    GLD16(vp + (size_t)srow * 2048 + (kt) * 64 + ssw * 8, &lV[buf][tid * 8]); \
    GLD16(vp + (size_t)(srow + 32) * 2048 + (kt) * 64 + ssw * 8, &lV[buf][(tid + 256) * 8]); \
} while (0)

    // Q fragments, hoisted (A-frag: row = c, k = kc*32 + g*8)
    f16x8 aQ[2];
#pragma unroll
    for (int kc = 0; kc < 2; ++kc)
        aQ[kc] = *(const f16x8*)(qp + (size_t)c * 512 + kc * 32 + g * 8);

    float mrow[4], lrow[4];
    f32x4 o[4];
#pragma unroll
    for (int r = 0; r < 4; ++r) { mrow[r] = -1e30f; lrow[r] = 0.f; }
#pragma unroll
    for (int d = 0; d < 4; ++d) o[d] = (f32x4){0.f, 0.f, 0.f, 0.f};

    STAGE(0, 0);
    __syncthreads();   // drains vmcnt(0) before barrier

    for (int kt = 0; kt < 32; ++kt) {
        const int cur = kt & 1;
        if (kt < 31) STAGE(cur ^ 1, kt + 1);

        // ---- QK^T from lK[cur] ----
        f32x4 s[4];
        __builtin_amdgcn_s_setprio(1);
#pragma unroll
        for (int ks = 0; ks < 4; ++ks) {
            const int row = ks * 16 + c;
            f16x8 bk0 = *(const f16x8*)&lK[cur][row * 64 + (((0 * 4 + g) ^ (c & 7)) * 8)];
            f16x8 bk1 = *(const f16x8*)&lK[cur][row * 64 + (((1 * 4 + g) ^ (c & 7)) * 8)];
            f32x4 z = (f32x4){0.f, 0.f, 0.f, 0.f};
            z = __builtin_amdgcn_mfma_f32_16x16x32_f16(aQ[0], bk0, z, 0, 0, 0);
            z = __builtin_amdgcn_mfma_f32_16x16x32_f16(aQ[1], bk1, z, 0, 0, 0);
            s[ks] = z;
        }
        __builtin_amdgcn_s_setprio(0);

        // ---- online softmax (rows = g*4+r; 16 lanes of same g share a row) ----
        float sc[4];
#pragma unroll
        for (int r = 0; r < 4; ++r) {
            float pm = fmaxf(fmaxf(s[0][r], s[1][r]), fmaxf(s[2][r], s[3][r]));
            pm = fmaxf(pm, __shfl_xor(pm, 1));
            pm = fmaxf(pm, __shfl_xor(pm, 2));
            pm = fmaxf(pm, __shfl_xor(pm, 4));
            pm = fmaxf(pm, __shfl_xor(pm, 8));
            float nm = fmaxf(mrow[r], pm);
            float e = __expf(mrow[r] - nm);
            mrow[r] = nm;
            sc[r] = e;
            float rs = 0.f;
#pragma unroll
            for (int ks = 0; ks < 4; ++ks) {
                float p = __expf(s[ks][r] - nm);
                s[ks][r] = p;
                rs += p;
            }
            rs += __shfl_xor(rs, 1);
            rs += __shfl_xor(rs, 2);
            rs += __shfl_xor(rs, 4);
            rs += __shfl_xor(rs, 8);
            lrow[r] = lrow[r] * e + rs;
        }

        // ---- P -> per-wave LDS (fp16, swizzled) ----
#pragma unroll
        for (int ks = 0; ks < 4; ++ks)
#pragma unroll
            for (int r = 0; r < 4; ++r) {
                int row = g * 4 + r;
                int ch = (ks * 2 + (c >> 3)) ^ (row & 7);
                myp[row * 64 + ch * 8 + (c & 7)] = (_Float16)s[ks][r];
            }
        asm volatile("s_waitcnt lgkmcnt(0)" ::: "memory");
        __builtin_amdgcn_sched_barrier(0);

        // ---- P A-frags (row = c, key = kc*32 + g*8 + j) ----
        f16x8 aP[2];
#pragma unroll
        for (int kc = 0; kc < 2; ++kc) {
            int ch = (kc * 4 + g) ^ (c & 7);
            aP[kc] = *(const f16x8*)&myp[c * 64 + ch * 8];
        }

        // ---- rescale O ----
#pragma unroll
        for (int d = 0; d < 4; ++d)
#pragma unroll
            for (int r = 0; r < 4; ++r) o[d][r] *= sc[r];

        // ---- PV from lV[cur] ----
        __builtin_amdgcn_s_setprio(1);
#pragma unroll
        for (int d = 0; d < 4; ++d) {
            const int row = d * 16 + c;
            f16x8 bv0 = *(const f16x8*)&lV[cur][row * 64 + (((0 * 4 + g) ^ (c & 7)) * 8)];
            f16x8 bv1 = *(const f16x8*)&lV[cur][row * 64 + (((1 * 4 + g) ^ (c & 7)) * 8)];
            o[d] = __builtin_amdgcn_mfma_f32_16x16x32_f16(aP[0], bv0, o[d], 0, 0, 0);
            o[d] = __builtin_amdgcn_mfma_f32_16x16x32_f16(aP[1], bv1, o[d], 0, 0, 0);
        }
        __builtin_amdgcn_s_setprio(0);

        __syncthreads();   // staged tile kt+1 complete (vmcnt drained) + buf reads done
    }

    // ---- epilogue: divide by l, store fp32 ----
#pragma unroll
    for (int d = 0; d < 4; ++d)
#pragma unroll
        for (int r = 0; r < 4; ++r) {
            int qrow = qb * 64 + wid * 16 + g * 4 + r;
            out[((size_t)b * 2048 + qrow) * 512 + h * 64 + d * 16 + c] =
                o[d][r] / lrow[r];
        }
#undef STAGE
}

extern "C" void kernel_launch(void* const* d_in, const int* in_sizes, int n_in,
                              void* d_out, int out_size, void* d_ws, size_t ws_size,
                              hipStream_t stream) {
    const float* x = (const float*)d_in[0];
    const float* Wq = (const float*)d_in[1];
    const float* Wk = (const float*)d_in[2];
    const float* Wv = (const float*)d_in[3];
    float* out = (float*)d_out;
    float* xcopy = out + 4194304;

    char* ws = (char*)d_ws;
    _Float16* xh = (_Float16*)ws;                          // 8 MB
    _Float16* wt = (_Float16*)(ws + (size_t)(10u << 20));  // 1.5 MB
    _Float16* qh = (_Float16*)(ws + (size_t)(12u << 20));  // 8 MB
    _Float16* kh = (_Float16*)(ws + (size_t)(20u << 20));  // 8 MB
    _Float16* vt = (_Float16*)(ws + (size_t)(28u << 20));  // 8 MB

    cvt_x_kernel<<<2048, 256, 0, stream>>>((const float4*)x, (f16x8*)xh, (float4*)xcopy, 524288);
    cvt_w_kernel<<<3072, 256, 0, stream>>>(Wq, Wk, Wv, wt);
    gemm_qkv<<<dim3(256, 3), 256, 0, stream>>>(xh, wt, qh, kh, vt);
    attn_kernel<<<1024, 256, 0, stream>>>(qh, kh, vt, out);
}

// Round 4
// 108.798 us; speedup vs baseline: 1.9128x; 1.3409x over previous
//
#include <hip/hip_runtime.h>

typedef _Float16 f16x8 __attribute__((ext_vector_type(8)));
typedef float f32x4 __attribute__((ext_vector_type(4)));

#define GF(r) ((((r)&3)) ^ (((r)>>2)&3))
#define LOG2E 1.44269504088896f

#define GLD16(gp, lp) __builtin_amdgcn_global_load_lds( \
    (const __attribute__((address_space(1))) void*)(gp), \
    (__attribute__((address_space(3))) void*)(lp), 16, 0, 0)

// ---------------- kernel 1: x -> fp16, and fp32 passthrough copy ----------------
__global__ void cvt_x_kernel(const float4* __restrict__ x4, f16x8* __restrict__ xh,
                             float4* __restrict__ xc, int n8) {
    int i = blockIdx.x * 256 + threadIdx.x;
    if (i >= n8) return;
    float4 a = x4[2 * i], b = x4[2 * i + 1];
    xc[2 * i] = a;
    xc[2 * i + 1] = b;
    f16x8 h;
    h[0] = (_Float16)a.x; h[1] = (_Float16)a.y; h[2] = (_Float16)a.z; h[3] = (_Float16)a.w;
    h[4] = (_Float16)b.x; h[5] = (_Float16)b.y; h[6] = (_Float16)b.z; h[7] = (_Float16)b.w;
    xh[i] = h;
}

// ---------------- kernel 2: W -> W^T fp16 (wt[mat][n][k]) ----------------
__global__ void cvt_w_kernel(const float* __restrict__ Wq, const float* __restrict__ Wk,
                             const float* __restrict__ Wv, _Float16* __restrict__ wt) {
    int j = blockIdx.x * 256 + threadIdx.x;   // 3*512*512 = 786432
    if (j >= 786432) return;
    int mat = j >> 18;
    int r = (j >> 9) & 511;   // k index (input row)
    int n = j & 511;          // output column
    const float* W = (mat == 0) ? Wq : ((mat == 1) ? Wk : Wv);
    float v = W[r * 512 + n];
    wt[(size_t)mat * 262144 + (size_t)n * 512 + r] = (_Float16)v;
}

// ---------------- kernel 3: QKV projection GEMM (fp16 MFMA) ----------------
__global__ __launch_bounds__(256, 2) void gemm_qkv(
    const _Float16* __restrict__ xh, const _Float16* __restrict__ wt,
    _Float16* __restrict__ qh, _Float16* __restrict__ kh, _Float16* __restrict__ vt) {
    __shared__ _Float16 lA[128 * 32];
    __shared__ _Float16 lB[128 * 32];
    const int mat = blockIdx.y;
    const _Float16* wp = wt + (size_t)mat * 262144;
    const int mtile = blockIdx.x >> 2, ntile = blockIdx.x & 3;
    const int tid = threadIdx.x, lane = tid & 63;
    const int g = lane >> 4, c = lane & 15;
    const int wid = tid >> 6, wm = wid >> 1, wn = wid & 1;

    f32x4 acc[4][4];
#pragma unroll
    for (int i = 0; i < 4; ++i)
#pragma unroll
        for (int j = 0; j < 4; ++j) acc[i][j] = (f32x4){0.f, 0.f, 0.f, 0.f};

    const int row0 = tid >> 2, p0 = tid & 3;

    for (int ks = 0; ks < 16; ++ks) {
        __syncthreads();
        {
            int r = row0, pp = p0 ^ GF(r);
            GLD16(xh + (size_t)(mtile * 128 + r) * 512 + ks * 32 + pp * 8, &lA[tid * 8]);
            GLD16(wp + (size_t)(ntile * 128 + r) * 512 + ks * 32 + pp * 8, &lB[tid * 8]);
            r = 64 + row0; pp = p0 ^ GF(r);
            GLD16(xh + (size_t)(mtile * 128 + r) * 512 + ks * 32 + pp * 8, &lA[(256 + tid) * 8]);
            GLD16(wp + (size_t)(ntile * 128 + r) * 512 + ks * 32 + pp * 8, &lB[(256 + tid) * 8]);
        }
        __syncthreads();
        f16x8 af[4], bf[4];
#pragma unroll
        for (int i = 0; i < 4; ++i) {
            int ra = wm * 64 + i * 16 + c;
            af[i] = *(const f16x8*)&lA[ra * 32 + ((g ^ GF(ra)) * 8)];
            int rb = wn * 64 + i * 16 + c;
            bf[i] = *(const f16x8*)&lB[rb * 32 + ((g ^ GF(rb)) * 8)];
        }
#pragma unroll
        for (int mi = 0; mi < 4; ++mi)
#pragma unroll
            for (int ni = 0; ni < 4; ++ni)
                acc[mi][ni] = __builtin_amdgcn_mfma_f32_16x16x32_f16(af[mi], bf[ni], acc[mi][ni], 0, 0, 0);
    }

#pragma unroll
    for (int mi = 0; mi < 4; ++mi)
#pragma unroll
        for (int ni = 0; ni < 4; ++ni)
#pragma unroll
            for (int r = 0; r < 4; ++r) {
                int m = mtile * 128 + wm * 64 + mi * 16 + g * 4 + r;
                int n = ntile * 128 + wn * 64 + ni * 16 + c;
                _Float16 hv = (_Float16)acc[mi][ni][r];
                if (mat == 0) {
                    qh[(size_t)m * 512 + n] = hv;
                } else if (mat == 1) {
                    kh[(size_t)m * 512 + n] = hv;
                } else {
                    int h = n >> 6, d = n & 63, bb = m >> 11, s = m & 2047;
                    vt[(((size_t)h * 4 + bb) * 64 + d) * 2048 + s] = hv;
                }
            }
}

// ---------------- kernel 4: flash attention (swapped QK^T, lane-local softmax) --
// grid 1024: xcd-grouped (h,b); 4 waves x 16 q-rows = 64 q-rows per block.
__global__ __launch_bounds__(256, 4) void attn_kernel(
    const _Float16* __restrict__ qh, const _Float16* __restrict__ kh,
    const _Float16* __restrict__ vt, float* __restrict__ out) {
    __shared__ _Float16 lK[2][64 * 64];   // [key][dh], chunk-swizzled
    __shared__ _Float16 lV[2][64 * 64];   // [dh][key], chunk-swizzled
    __shared__ _Float16 lP[4][16 * 64];   // per-wave P^T buffer [q][key], swizzled

    const int bid = blockIdx.x;
    const int xcd = bid & 7, idx = bid >> 3;     // idx 0..127
    const int hb = xcd * 4 + (idx >> 5);         // 0..31 (4 hb per XCD)
    const int qb = idx & 31;                     // 0..31
    const int h = hb >> 2, b = hb & 3;
    const int tid = threadIdx.x, lane = tid & 63, wid = tid >> 6;
    const int g = lane >> 4, c = lane & 15;

    const _Float16* qp = qh + ((size_t)b * 2048 + qb * 64 + wid * 16) * 512 + h * 64;
    const _Float16* kp = kh + (size_t)b * 2048 * 512 + h * 64;
    const _Float16* vp = vt + (size_t)hb * 64 * 2048;
    _Float16* myp = lP[wid];

    const int srow = tid >> 3;                 // 0..31
    const int ssw = (tid & 7) ^ (srow & 7);

#define STAGE(buf, kt) do { \
    GLD16(kp + ((size_t)((kt) * 64 + srow) * 512) + ssw * 8, &lK[buf][tid * 8]); \
    GLD16(kp + ((size_t)((kt) * 64 + srow + 32) * 512) + ssw * 8, &lK[buf][(tid + 256) * 8]); \
    GLD16(vp + (size_t)srow * 2048 + (kt) * 64 + ssw * 8, &lV[buf][tid * 8]); \
    GLD16(vp + (size_t)(srow + 32) * 2048 + (kt) * 64 + ssw * 8, &lV[buf][(tid + 256) * 8]); \
} while (0)

    // Q fragments (used as MFMA *B* operand: col = qrow = c, k = kc*32 + g*8 + j)
    f16x8 aQ[2];
#pragma unroll
    for (int kc = 0; kc < 2; ++kc)
        aQ[kc] = *(const f16x8*)(qp + (size_t)c * 512 + kc * 32 + g * 8);

    float mrow = -1e30f, lrow = 0.f;   // lane-local: one q-row per lane
    f32x4 o[4];                        // O^T: d-block db, d = db*16 + 4g + r
#pragma unroll
    for (int d = 0; d < 4; ++d) o[d] = (f32x4){0.f, 0.f, 0.f, 0.f};

    STAGE(0, 0);
    __syncthreads();

    for (int kt = 0; kt < 32; ++kt) {
        const int cur = kt & 1;
        if (kt < 31) STAGE(cur ^ 1, kt + 1);

        // ---- S^T = K * Q^T : s[kb] holds keys kb*16 + 4g + r, qrow c ----
        f32x4 s[4];
        __builtin_amdgcn_s_setprio(1);
#pragma unroll
        for (int kb = 0; kb < 4; ++kb) {
            const int row = kb * 16 + c;
            f16x8 ak0 = *(const f16x8*)&lK[cur][row * 64 + ((g ^ (c & 7)) * 8)];
            f16x8 ak1 = *(const f16x8*)&lK[cur][row * 64 + (((4 + g) ^ (c & 7)) * 8)];
            f32x4 z = (f32x4){0.f, 0.f, 0.f, 0.f};
            z = __builtin_amdgcn_mfma_f32_16x16x32_f16(ak0, aQ[0], z, 0, 0, 0);
            z = __builtin_amdgcn_mfma_f32_16x16x32_f16(ak1, aQ[1], z, 0, 0, 0);
            s[kb] = z;
        }
        __builtin_amdgcn_s_setprio(0);

        // ---- lane-local online softmax (base-2 domain) ----
        float pm;
        {
            float m0 = fmaxf(fmaxf(s[0][0], s[0][1]), fmaxf(s[0][2], s[0][3]));
            float m1 = fmaxf(fmaxf(s[1][0], s[1][1]), fmaxf(s[1][2], s[1][3]));
            float m2 = fmaxf(fmaxf(s[2][0], s[2][1]), fmaxf(s[2][2], s[2][3]));
            float m3 = fmaxf(fmaxf(s[3][0], s[3][1]), fmaxf(s[3][2], s[3][3]));
            pm = fmaxf(fmaxf(m0, m1), fmaxf(m2, m3));
        }
        pm = fmaxf(pm, __shfl_xor(pm, 16));
        pm = fmaxf(pm, __shfl_xor(pm, 32));
        const float nm = fmaxf(mrow, pm);
        const float nm2 = nm * LOG2E;
        const float e = __builtin_amdgcn_exp2f(mrow * LOG2E - nm2);
        mrow = nm;

        float rs;
        {
            float a0 = 0.f, a1 = 0.f, a2 = 0.f, a3 = 0.f;
#pragma unroll
            for (int kb = 0; kb < 4; ++kb) {
                float p0 = __builtin_amdgcn_exp2f(fmaf(s[kb][0], LOG2E, -nm2));
                float p1 = __builtin_amdgcn_exp2f(fmaf(s[kb][1], LOG2E, -nm2));
                float p2 = __builtin_amdgcn_exp2f(fmaf(s[kb][2], LOG2E, -nm2));
                float p3 = __builtin_amdgcn_exp2f(fmaf(s[kb][3], LOG2E, -nm2));
                s[kb][0] = p0; s[kb][1] = p1; s[kb][2] = p2; s[kb][3] = p3;
                a0 += p0; a1 += p1; a2 += p2; a3 += p3;
            }
            rs = (a0 + a1) + (a2 + a3);
        }
        rs += __shfl_xor(rs, 16);
        rs += __shfl_xor(rs, 32);
        lrow = lrow * e + rs;

        // ---- P^T -> per-wave LDS (packed f16 pairs, swizzled 8B writes) ----
#pragma unroll
        for (int kb = 0; kb < 4; ++kb) {
            unsigned int ulo = __builtin_bit_cast(unsigned int,
                __builtin_amdgcn_cvt_pkrtz(s[kb][0], s[kb][1]));
            unsigned int uhi = __builtin_bit_cast(unsigned int,
                __builtin_amdgcn_cvt_pkrtz(s[kb][2], s[kb][3]));
            int ch = (2 * kb + (g >> 1)) ^ (c & 7);
            uint2 pk; pk.x = ulo; pk.y = uhi;
            *(uint2*)&myp[c * 64 + ch * 8 + 4 * (g & 1)] = pk;
        }

        // ---- rescale O (overlaps ds_write latency) ----
#pragma unroll
        for (int d = 0; d < 4; ++d)
#pragma unroll
            for (int r = 0; r < 4; ++r) o[d][r] *= e;

        asm volatile("s_waitcnt lgkmcnt(0)" ::: "memory");
        __builtin_amdgcn_sched_barrier(0);

        // ---- P B-frags (col = qrow = c, k = key = ks*32 + 8g + j) ----
        f16x8 aP[2];
#pragma unroll
        for (int ks = 0; ks < 2; ++ks) {
            int ch = (4 * ks + g) ^ (c & 7);
            aP[ks] = *(const f16x8*)&myp[c * 64 + ch * 8];
        }

        // ---- O^T += V^T * P : A = V^T[d-slice][keys] from lV ----
        __builtin_amdgcn_s_setprio(1);
#pragma unroll
        for (int db = 0; db < 4; ++db) {
            const int row = db * 16 + c;
            f16x8 av0 = *(const f16x8*)&lV[cur][row * 64 + ((g ^ (c & 7)) * 8)];
            f16x8 av1 = *(const f16x8*)&lV[cur][row * 64 + (((4 + g) ^ (c & 7)) * 8)];
            o[db] = __builtin_amdgcn_mfma_f32_16x16x32_f16(av0, aP[0], o[db], 0, 0, 0);
            o[db] = __builtin_amdgcn_mfma_f32_16x16x32_f16(av1, aP[1], o[db], 0, 0, 0);
        }
        __builtin_amdgcn_s_setprio(0);

        __syncthreads();
    }

    // ---- epilogue: divide by l, store fp32 (float4 per d-block) ----
    const float inv = 1.0f / lrow;
    const int qrow = qb * 64 + wid * 16 + c;
    float* op = out + ((size_t)b * 2048 + qrow) * 512 + h * 64;
#pragma unroll
    for (int db = 0; db < 4; ++db) {
        float4 st;
        st.x = o[db][0] * inv;
        st.y = o[db][1] * inv;
        st.z = o[db][2] * inv;
        st.w = o[db][3] * inv;
        *(float4*)(op + db * 16 + 4 * g) = st;
    }
#undef STAGE
}

extern "C" void kernel_launch(void* const* d_in, const int* in_sizes, int n_in,
                              void* d_out, int out_size, void* d_ws, size_t ws_size,
                              hipStream_t stream) {
    const float* x = (const float*)d_in[0];
    const float* Wq = (const float*)d_in[1];
    const float* Wk = (const float*)d_in[2];
    const float* Wv = (const float*)d_in[3];
    float* out = (float*)d_out;
    float* xcopy = out + 4194304;

    char* ws = (char*)d_ws;
    _Float16* xh = (_Float16*)ws;                          // 8 MB
    _Float16* wt = (_Float16*)(ws + (size_t)(10u << 20));  // 1.5 MB
    _Float16* qh = (_Float16*)(ws + (size_t)(12u << 20));  // 8 MB
    _Float16* kh = (_Float16*)(ws + (size_t)(20u << 20));  // 8 MB
    _Float16* vt = (_Float16*)(ws + (size_t)(28u << 20));  // 8 MB

    cvt_x_kernel<<<2048, 256, 0, stream>>>((const float4*)x, (f16x8*)xh, (float4*)xcopy, 524288);
    cvt_w_kernel<<<3072, 256, 0, stream>>>(Wq, Wk, Wv, wt);
    gemm_qkv<<<dim3(256, 3), 256, 0, stream>>>(xh, wt, qh, kh, vt);
    attn_kernel<<<1024, 256, 0, stream>>>(qh, kh, vt, out);
}

// Round 5
// 99.794 us; speedup vs baseline: 2.0854x; 1.0902x over previous
//
#include <hip/hip_runtime.h>

typedef _Float16 f16x8 __attribute__((ext_vector_type(8)));
typedef float f32x4 __attribute__((ext_vector_type(4)));
typedef float f32x16 __attribute__((ext_vector_type(16)));

#define GF(r) ((((r)&3)) ^ (((r)>>2)&3))
#define LOG2E 1.44269504088896f

#define GLD16(gp, lp) __builtin_amdgcn_global_load_lds( \
    (const __attribute__((address_space(1))) void*)(gp), \
    (__attribute__((address_space(3))) void*)(lp), 16, 0, 0)

// ---------------- kernel 1: x -> fp16, and fp32 passthrough copy ----------------
__global__ void cvt_x_kernel(const float4* __restrict__ x4, f16x8* __restrict__ xh,
                             float4* __restrict__ xc, int n8) {
    int i = blockIdx.x * 256 + threadIdx.x;
    if (i >= n8) return;
    float4 a = x4[2 * i], b = x4[2 * i + 1];
    xc[2 * i] = a;
    xc[2 * i + 1] = b;
    f16x8 h;
    h[0] = (_Float16)a.x; h[1] = (_Float16)a.y; h[2] = (_Float16)a.z; h[3] = (_Float16)a.w;
    h[4] = (_Float16)b.x; h[5] = (_Float16)b.y; h[6] = (_Float16)b.z; h[7] = (_Float16)b.w;
    xh[i] = h;
}

// ---------------- kernel 2: W -> W^T fp16 (wt[mat][n][k]) ----------------
__global__ void cvt_w_kernel(const float* __restrict__ Wq, const float* __restrict__ Wk,
                             const float* __restrict__ Wv, _Float16* __restrict__ wt) {
    int j = blockIdx.x * 256 + threadIdx.x;   // 3*512*512 = 786432
    if (j >= 786432) return;
    int mat = j >> 18;
    int r = (j >> 9) & 511;
    int n = j & 511;
    const float* W = (mat == 0) ? Wq : ((mat == 1) ? Wk : Wv);
    float v = W[r * 512 + n];
    wt[(size_t)mat * 262144 + (size_t)n * 512 + r] = (_Float16)v;
}

// ---------------- kernel 3: QKV projection GEMM (fp16 MFMA) ----------------
__global__ __launch_bounds__(256, 2) void gemm_qkv(
    const _Float16* __restrict__ xh, const _Float16* __restrict__ wt,
    _Float16* __restrict__ qh, _Float16* __restrict__ kh, _Float16* __restrict__ vt) {
    __shared__ _Float16 lA[128 * 32];
    __shared__ _Float16 lB[128 * 32];
    const int mat = blockIdx.y;
    const _Float16* wp = wt + (size_t)mat * 262144;
    const int mtile = blockIdx.x >> 2, ntile = blockIdx.x & 3;
    const int tid = threadIdx.x, lane = tid & 63;
    const int g = lane >> 4, c = lane & 15;
    const int wid = tid >> 6, wm = wid >> 1, wn = wid & 1;

    f32x4 acc[4][4];
#pragma unroll
    for (int i = 0; i < 4; ++i)
#pragma unroll
        for (int j = 0; j < 4; ++j) acc[i][j] = (f32x4){0.f, 0.f, 0.f, 0.f};

    const int row0 = tid >> 2, p0 = tid & 3;

    for (int ks = 0; ks < 16; ++ks) {
        __syncthreads();
        {
            int r = row0, pp = p0 ^ GF(r);
            GLD16(xh + (size_t)(mtile * 128 + r) * 512 + ks * 32 + pp * 8, &lA[tid * 8]);
            GLD16(wp + (size_t)(ntile * 128 + r) * 512 + ks * 32 + pp * 8, &lB[tid * 8]);
            r = 64 + row0; pp = p0 ^ GF(r);
            GLD16(xh + (size_t)(mtile * 128 + r) * 512 + ks * 32 + pp * 8, &lA[(256 + tid) * 8]);
            GLD16(wp + (size_t)(ntile * 128 + r) * 512 + ks * 32 + pp * 8, &lB[(256 + tid) * 8]);
        }
        __syncthreads();
        f16x8 af[4], bf[4];
#pragma unroll
        for (int i = 0; i < 4; ++i) {
            int ra = wm * 64 + i * 16 + c;
            af[i] = *(const f16x8*)&lA[ra * 32 + ((g ^ GF(ra)) * 8)];
            int rb = wn * 64 + i * 16 + c;
            bf[i] = *(const f16x8*)&lB[rb * 32 + ((g ^ GF(rb)) * 8)];
        }
#pragma unroll
        for (int mi = 0; mi < 4; ++mi)
#pragma unroll
            for (int ni = 0; ni < 4; ++ni)
                acc[mi][ni] = __builtin_amdgcn_mfma_f32_16x16x32_f16(af[mi], bf[ni], acc[mi][ni], 0, 0, 0);
    }

#pragma unroll
    for (int mi = 0; mi < 4; ++mi)
#pragma unroll
        for (int ni = 0; ni < 4; ++ni)
#pragma unroll
            for (int r = 0; r < 4; ++r) {
                int m = mtile * 128 + wm * 64 + mi * 16 + g * 4 + r;
                int n = ntile * 128 + wn * 64 + ni * 16 + c;
                _Float16 hv = (_Float16)acc[mi][ni][r];
                if (mat == 0) {
                    qh[(size_t)m * 512 + n] = hv;
                } else if (mat == 1) {
                    kh[(size_t)m * 512 + n] = hv;
                } else {
                    int h = n >> 6, d = n & 63, bb = m >> 11, s = m & 2047;
                    vt[(((size_t)h * 4 + bb) * 64 + d) * 2048 + s] = hv;
                }
            }
}

// ---------------- kernel 4: flash attention, 32x32 MFMA, in-register P ----------
// grid 512: xcd-grouped (h,b); 4 waves x 32 q-rows = 128 q-rows per block.
__global__ __launch_bounds__(256, 2) void attn_kernel(
    const _Float16* __restrict__ qh, const _Float16* __restrict__ kh,
    const _Float16* __restrict__ vt, float* __restrict__ out) {
    __shared__ _Float16 lK[2][64 * 64];   // [key][dh], chunk-swizzled
    __shared__ _Float16 lV[2][64 * 64];   // [dh][key], chunk-swizzled
    __shared__ float eb[4][64 * 33];      // per-wave epilogue transpose buffer

    const int bid = blockIdx.x;
    const int xcd = bid & 7, idx = bid >> 3;     // idx 0..63
    const int hb = xcd * 4 + (idx >> 4);         // 0..31 (4 hb per XCD)
    const int qblk = idx & 15;                   // 0..15
    const int h = hb >> 2, b = hb & 3;
    const int tid = threadIdx.x, lane = tid & 63, wid = tid >> 6;
    const int q = lane & 31, hi = lane >> 5;

    const int qrow0 = qblk * 128 + wid * 32;
    const _Float16* qp = qh + ((size_t)b * 2048 + qrow0) * 512 + h * 64;
    const _Float16* kp = kh + (size_t)b * 2048 * 512 + h * 64;
    const _Float16* vp = vt + (size_t)hb * 64 * 2048;

    const int srow = tid >> 3;                 // 0..31
    const int ssw = (tid & 7) ^ (srow & 7);

#define STAGE(buf, kt) do { \
    GLD16(kp + ((size_t)((kt) * 64 + srow) * 512) + ssw * 8, &lK[buf][tid * 8]); \
    GLD16(kp + ((size_t)((kt) * 64 + srow + 32) * 512) + ssw * 8, &lK[buf][(tid + 256) * 8]); \
    GLD16(vp + (size_t)srow * 2048 + (kt) * 64 + ssw * 8, &lV[buf][tid * 8]); \
    GLD16(vp + (size_t)(srow + 32) * 2048 + (kt) * 64 + ssw * 8, &lV[buf][(tid + 256) * 8]); \
} while (0)

    // Q fragments (MFMA B operand: col = q, k = kc*16 + hi*8 + j)
    f16x8 aQ[4];
#pragma unroll
    for (int kc = 0; kc < 4; ++kc)
        aQ[kc] = *(const f16x8*)(qp + (size_t)q * 512 + kc * 16 + hi * 8);

    float mrow = -1e30f, lrow = 0.f;
    f32x16 o0, o1;   // O^T d-blocks: row d = db*32 + (i&3)+8*(i>>2)+4*hi, col q
#pragma unroll
    for (int i = 0; i < 16; ++i) { o0[i] = 0.f; o1[i] = 0.f; }

    STAGE(0, 0);
    __syncthreads();

    for (int kt = 0; kt < 32; ++kt) {
        const int cur = kt & 1;
        if (kt < 31) STAGE(cur ^ 1, kt + 1);

        // ---- S^T = K * Q^T : s0/s1 = key-blocks 0/1; key = kb*32+(i&3)+8*(i>>2)+4*hi
        f32x16 s0, s1;
        __builtin_amdgcn_s_setprio(1);
        {
            f32x16 z0, z1;
#pragma unroll
            for (int i = 0; i < 16; ++i) { z0[i] = 0.f; z1[i] = 0.f; }
            const int r0 = q, r1 = 32 + q, sw = q & 7;
#pragma unroll
            for (int kc = 0; kc < 4; ++kc) {
                f16x8 ak0 = *(const f16x8*)&lK[cur][r0 * 64 + (((2 * kc + hi) ^ sw) * 8)];
                f16x8 ak1 = *(const f16x8*)&lK[cur][r1 * 64 + (((2 * kc + hi) ^ sw) * 8)];
                z0 = __builtin_amdgcn_mfma_f32_32x32x16_f16(ak0, aQ[kc], z0, 0, 0, 0);
                z1 = __builtin_amdgcn_mfma_f32_32x32x16_f16(ak1, aQ[kc], z1, 0, 0, 0);
            }
            s0 = z0; s1 = z1;
        }
        __builtin_amdgcn_s_setprio(0);

        // ---- lane-local online softmax over 32 values (+1 shfl for hi-halves) ----
        float pm;
        {
            float m0 = fmaxf(fmaxf(s0[0], s0[1]), fmaxf(s0[2], s0[3]));
            float m1 = fmaxf(fmaxf(s0[4], s0[5]), fmaxf(s0[6], s0[7]));
            float m2 = fmaxf(fmaxf(s0[8], s0[9]), fmaxf(s0[10], s0[11]));
            float m3 = fmaxf(fmaxf(s0[12], s0[13]), fmaxf(s0[14], s0[15]));
            float m4 = fmaxf(fmaxf(s1[0], s1[1]), fmaxf(s1[2], s1[3]));
            float m5 = fmaxf(fmaxf(s1[4], s1[5]), fmaxf(s1[6], s1[7]));
            float m6 = fmaxf(fmaxf(s1[8], s1[9]), fmaxf(s1[10], s1[11]));
            float m7 = fmaxf(fmaxf(s1[12], s1[13]), fmaxf(s1[14], s1[15]));
            pm = fmaxf(fmaxf(fmaxf(m0, m1), fmaxf(m2, m3)),
                       fmaxf(fmaxf(m4, m5), fmaxf(m6, m7)));
        }
        pm = fmaxf(pm, __shfl_xor(pm, 32));
        const float nm = fmaxf(mrow, pm);
        const float nm2 = nm * LOG2E;
        const float e = __builtin_amdgcn_exp2f(mrow * LOG2E - nm2);
        mrow = nm;

        float rs;
        {
            float a0 = 0.f, a1 = 0.f, a2 = 0.f, a3 = 0.f;
#pragma unroll
            for (int i = 0; i < 4; ++i) {
                float p0 = __builtin_amdgcn_exp2f(fmaf(s0[4 * i + 0], LOG2E, -nm2));
                float p1 = __builtin_amdgcn_exp2f(fmaf(s0[4 * i + 1], LOG2E, -nm2));
                float p2 = __builtin_amdgcn_exp2f(fmaf(s0[4 * i + 2], LOG2E, -nm2));
                float p3 = __builtin_amdgcn_exp2f(fmaf(s0[4 * i + 3], LOG2E, -nm2));
                s0[4 * i + 0] = p0; s0[4 * i + 1] = p1; s0[4 * i + 2] = p2; s0[4 * i + 3] = p3;
                a0 += p0; a1 += p1; a2 += p2; a3 += p3;
            }
#pragma unroll
            for (int i = 0; i < 4; ++i) {
                float p0 = __builtin_amdgcn_exp2f(fmaf(s1[4 * i + 0], LOG2E, -nm2));
                float p1 = __builtin_amdgcn_exp2f(fmaf(s1[4 * i + 1], LOG2E, -nm2));
                float p2 = __builtin_amdgcn_exp2f(fmaf(s1[4 * i + 2], LOG2E, -nm2));
                float p3 = __builtin_amdgcn_exp2f(fmaf(s1[4 * i + 3], LOG2E, -nm2));
                s1[4 * i + 0] = p0; s1[4 * i + 1] = p1; s1[4 * i + 2] = p2; s1[4 * i + 3] = p3;
                a0 += p0; a1 += p1; a2 += p2; a3 += p3;
            }
            rs = (a0 + a1) + (a2 + a3);
        }
        rs += __shfl_xor(rs, 32);
        lrow = lrow * e + rs;

        // ---- rescale O ----
        o0 *= e;
        o1 *= e;

        // ---- P -> f16 B-frags in registers (cvt_pkrtz + permlane32_swap) ----
        // per 32-key block: t[p] = pack(s[2p], s[2p+1]); swap(t0,t2),(t1,t3) ->
        // frag(chunk0) = {t0,t1,t2,t3}; swap(t4,t6),(t5,t7) -> frag(chunk1).
        f16x8 pf[4];
#pragma unroll
        for (int kb = 0; kb < 2; ++kb) {
            const f32x16& sv = kb ? s1 : s0;
            unsigned t0 = __builtin_bit_cast(unsigned, __builtin_amdgcn_cvt_pkrtz(sv[0], sv[1]));
            unsigned t1 = __builtin_bit_cast(unsigned, __builtin_amdgcn_cvt_pkrtz(sv[2], sv[3]));
            unsigned t2 = __builtin_bit_cast(unsigned, __builtin_amdgcn_cvt_pkrtz(sv[4], sv[5]));
            unsigned t3 = __builtin_bit_cast(unsigned, __builtin_amdgcn_cvt_pkrtz(sv[6], sv[7]));
            unsigned t4 = __builtin_bit_cast(unsigned, __builtin_amdgcn_cvt_pkrtz(sv[8], sv[9]));
            unsigned t5 = __builtin_bit_cast(unsigned, __builtin_amdgcn_cvt_pkrtz(sv[10], sv[11]));
            unsigned t6 = __builtin_bit_cast(unsigned, __builtin_amdgcn_cvt_pkrtz(sv[12], sv[13]));
            unsigned t7 = __builtin_bit_cast(unsigned, __builtin_amdgcn_cvt_pkrtz(sv[14], sv[15]));
            asm volatile("v_permlane32_swap_b32 %0, %1" : "+v"(t0), "+v"(t2));
            asm volatile("v_permlane32_swap_b32 %0, %1" : "+v"(t1), "+v"(t3));
            asm volatile("v_permlane32_swap_b32 %0, %1" : "+v"(t4), "+v"(t6));
            asm volatile("v_permlane32_swap_b32 %0, %1" : "+v"(t5), "+v"(t7));
            uint4 u0; u0.x = t0; u0.y = t1; u0.z = t2; u0.w = t3;
            uint4 u1; u1.x = t4; u1.y = t5; u1.z = t6; u1.w = t7;
            pf[2 * kb + 0] = __builtin_bit_cast(f16x8, u0);
            pf[2 * kb + 1] = __builtin_bit_cast(f16x8, u1);
        }

        // ---- O^T += V^T * P ----
        __builtin_amdgcn_s_setprio(1);
        {
            const int d0 = q, d1 = 32 + q, sw = q & 7;
#pragma unroll
            for (int ck = 0; ck < 4; ++ck) {
                f16x8 av0 = *(const f16x8*)&lV[cur][d0 * 64 + (((2 * ck + hi) ^ sw) * 8)];
                f16x8 av1 = *(const f16x8*)&lV[cur][d1 * 64 + (((2 * ck + hi) ^ sw) * 8)];
                o0 = __builtin_amdgcn_mfma_f32_32x32x16_f16(av0, pf[ck], o0, 0, 0, 0);
                o1 = __builtin_amdgcn_mfma_f32_32x32x16_f16(av1, pf[ck], o1, 0, 0, 0);
            }
        }
        __builtin_amdgcn_s_setprio(0);

        __syncthreads();
    }

    // ---- epilogue: divide by l, transpose via per-wave LDS, coalesced stores ----
    const float inv = 1.0f / lrow;
    float* ebw = eb[wid];
#pragma unroll
    for (int i = 0; i < 16; ++i) {
        int dr = (i & 3) + 8 * (i >> 2) + 4 * hi;
        ebw[dr * 33 + q] = o0[i] * inv;
        ebw[(32 + dr) * 33 + q] = o1[i] * inv;
    }
    __builtin_amdgcn_s_waitcnt(0);   // wave-local: lgkmcnt(0) before readback
    const int d0c = (lane & 15) * 4;
#pragma unroll
    for (int i = 0; i < 8; ++i) {
        int qr = 4 * i + (lane >> 4);
        float4 v;
        v.x = ebw[(d0c + 0) * 33 + qr];
        v.y = ebw[(d0c + 1) * 33 + qr];
        v.z = ebw[(d0c + 2) * 33 + qr];
        v.w = ebw[(d0c + 3) * 33 + qr];
        *(float4*)(out + ((size_t)b * 2048 + qrow0 + qr) * 512 + h * 64 + d0c) = v;
    }
#undef STAGE
}

extern "C" void kernel_launch(void* const* d_in, const int* in_sizes, int n_in,
                              void* d_out, int out_size, void* d_ws, size_t ws_size,
                              hipStream_t stream) {
    const float* x = (const float*)d_in[0];
    const float* Wq = (const float*)d_in[1];
    const float* Wk = (const float*)d_in[2];
    const float* Wv = (const float*)d_in[3];
    float* out = (float*)d_out;
    float* xcopy = out + 4194304;

    char* ws = (char*)d_ws;
    _Float16* xh = (_Float16*)ws;                          // 8 MB
    _Float16* wt = (_Float16*)(ws + (size_t)(10u << 20));  // 1.5 MB
    _Float16* qh = (_Float16*)(ws + (size_t)(12u << 20));  // 8 MB
    _Float16* kh = (_Float16*)(ws + (size_t)(20u << 20));  // 8 MB
    _Float16* vt = (_Float16*)(ws + (size_t)(28u << 20));  // 8 MB

    cvt_x_kernel<<<2048, 256, 0, stream>>>((const float4*)x, (f16x8*)xh, (float4*)xcopy, 524288);
    cvt_w_kernel<<<3072, 256, 0, stream>>>(Wq, Wk, Wv, wt);
    gemm_qkv<<<dim3(256, 3), 256, 0, stream>>>(xh, wt, qh, kh, vt);
    attn_kernel<<<512, 256, 0, stream>>>(qh, kh, vt, out);
}